// Round 1
// 324.604 us; speedup vs baseline: 1.0011x; 1.0011x over previous
//
#include <hip/hip_runtime.h>
#include <cstdint>

#define OWD 126
#define MTOT 15876   // 126*126

typedef short bf16x8 __attribute__((ext_vector_type(8)));
typedef float f32x4  __attribute__((ext_vector_type(4)));

#define BT_ELEMS  (16u * 128u * 1152u)                 // 2,359,296 bf16
#define XBF_ELEMS (16u * 128u * 128u * 128u)           // 33,554,432 bf16
#define WS_NEEDED ((size_t)(BT_ELEMS + XBF_ELEMS) * 2) // ~71.8 MB

__device__ __forceinline__ uint16_t f2bf(float f) {
    union { float f; uint32_t u; } v;
    v.f = f;
    uint32_t u = v.u;
    return (uint16_t)((u + 0x7FFFu + ((u >> 16) & 1u)) >> 16);
}

__device__ __forceinline__ uint32_t pk2(float a, float b) {
    return (uint32_t)f2bf(a) | ((uint32_t)f2bf(b) << 16);
}

__device__ __forceinline__ void gl_lds16(const uint16_t* g, uint16_t* l) {
    __builtin_amdgcn_global_load_lds(
        (const __attribute__((address_space(1))) uint32_t*)g,
        (__attribute__((address_space(3))) uint32_t*)l, 16, 0, 0);
}

// ---------------------------------------------------------------------------
// Prep 1: kernel [16][9][128 c][128 n] fp32 -> Bt [16][128 n][1152 k] bf16
// ---------------------------------------------------------------------------
__global__ __launch_bounds__(256) void kprep(const float* __restrict__ Kin,
                                             uint16_t* __restrict__ Bt) {
    const int rs = blockIdx.x;   // 0..8
    const int b  = blockIdx.y;   // 0..15
    const int t  = threadIdx.x;
    const int n  = t & 127;
    const int og = t >> 7;

    const float* src = Kin + (((size_t)b * 9 + rs) << 14);
    uint16_t*    dst = Bt + ((size_t)b * 128 + n) * 1152 + rs * 128;

#pragma unroll
    for (int o = 0; o < 8; ++o) {
        const int oct = og * 8 + o;
        const float* s0 = src + (oct * 8) * 128 + n;
        uint4 p;
        p.x = pk2(s0[0 * 128], s0[1 * 128]);
        p.y = pk2(s0[2 * 128], s0[3 * 128]);
        p.z = pk2(s0[4 * 128], s0[5 * 128]);
        p.w = pk2(s0[6 * 128], s0[7 * 128]);
        *(uint4*)(dst + oct * 8) = p;
    }
}

// ---------------------------------------------------------------------------
// Prep 2: X fp32 NHWC -> bf16 NHWC (same layout), 8 elems/thread
// ---------------------------------------------------------------------------
__global__ __launch_bounds__(256) void xprep(const float* __restrict__ X,
                                             uint16_t* __restrict__ Xbf) {
    const size_t i = ((size_t)blockIdx.x * 256 + threadIdx.x) * 8;
    const float4 a = *(const float4*)(X + i);
    const float4 b = *(const float4*)(X + i + 4);
    uint4 p;
    p.x = pk2(a.x, a.y);
    p.y = pk2(a.z, a.w);
    p.z = pk2(b.x, b.y);
    p.w = pk2(b.z, b.w);
    *(uint4*)(Xbf + i) = p;
}

// ---------------------------------------------------------------------------
// Main: implicit-GEMM conv. 128x128 C-tile per block, 18 chunks of BK=64.
// Round 1 change: 2-phase double-buffered pipeline (T3 "minimum 2-phase"):
//   STAGE(t+1 -> other buf) issued BEFORE ds_read+MFMA of chunk t; ONE
//   __syncthreads per chunk (its implicit vmcnt(0) drain now lands after the
//   MFMA phase instead of before it). Barriers/block: 36 -> 19.
// LDS layout (unchanged, verified conflict-free): tile [128 rows][64 k] bf16,
// 128B rows; logical 16B chunk kc of row r lives at slot kc^(r&7); staging
// lane l fetches chunk kc=(l&7)^(l>>3) so its fixed LDS dst (wave-uniform
// base + lane*16, per global_load_lds semantics) holds the right data.
// ---------------------------------------------------------------------------
__global__ __launch_bounds__(256) void conv_mfma_a(const uint16_t* __restrict__ Xbf,
                                                   const uint16_t* __restrict__ Bt,
                                                   float* __restrict__ Out) {
    __shared__ __align__(16) uint16_t lA[2][128 * 64];
    __shared__ __align__(16) uint16_t lB[2][128 * 64];

    const int mtile = blockIdx.x;  // 0..124
    const int b     = blockIdx.y;  // 0..15
    const int tid   = threadIdx.x;
    const int lane  = tid & 63;
    const int wave  = tid >> 6;
    const int wm    = (wave & 1) << 6;
    const int wn    = (wave >> 1) << 6;
    const int l15   = lane & 15;
    const int quad  = lane >> 4;

    // staging: lane l, iter i covers LDS slot s = wave*256 + i*64 + lane
    //   row = s>>3 = wave*32 + i*8 + (lane>>3), pslot = lane&7
    //   logical chunk kc = pslot ^ (row&7) = (lane&7) ^ (lane>>3)
    const int kc = (lane & 7) ^ (lane >> 3);
    const uint16_t* Asrc[4];
    const uint16_t* Bsrc[4];
#pragma unroll
    for (int i = 0; i < 4; ++i) {
        const int row = wave * 32 + i * 8 + (lane >> 3);
        int m = mtile * 128 + row;
        if (m >= MTOT) m = MTOT - 1;
        const int oh = m / OWD, ow = m - oh * OWD;
        Asrc[i] = Xbf + (((size_t)b * 128 + oh) * 128 + ow) * 128 + kc * 8;
        Bsrc[i] = Bt + ((size_t)b * 128 + row) * 1152 + kc * 8;
    }
    const int dbase = (wave * 256 + lane) * 8;

    f32x4 acc[4][4];
#pragma unroll
    for (int i = 0; i < 4; ++i)
#pragma unroll
        for (int j = 0; j < 4; ++j)
            acc[i][j] = (f32x4){0.f, 0.f, 0.f, 0.f};

    // chunk t (0..17): rs = t>>1, k-half c0 = (t&1)*64
#define STAGE(t_, bu_)                                                      \
    {                                                                       \
        const int rs_ = (t_) >> 1;                                         \
        const int c0_ = ((t_) & 1) << 6;                                   \
        const int r_  = (rs_ * 11) >> 5; /* rs/3 for rs<9 */               \
        const int s_  = rs_ - r_ * 3;                                      \
        const int ao_ = (r_ * 128 + s_) * 128 + c0_;                       \
        const int bo_ = rs_ * 128 + c0_;                                   \
        uint16_t* Ad_ = &lA[bu_][dbase];                                   \
        uint16_t* Bd_ = &lB[bu_][dbase];                                   \
        _Pragma("unroll")                                                  \
        for (int i_ = 0; i_ < 4; ++i_) {                                   \
            gl_lds16(Asrc[i_] + ao_, Ad_ + i_ * 512);                      \
            gl_lds16(Bsrc[i_] + bo_, Bd_ + i_ * 512);                      \
        }                                                                  \
    }

#define COMPUTE(bu_)                                                        \
    {                                                                       \
        _Pragma("unroll")                                                  \
        for (int ksub_ = 0; ksub_ < 2; ++ksub_) {                          \
            bf16x8 af[4], bfr[4];                                          \
            _Pragma("unroll")                                              \
            for (int i_ = 0; i_ < 4; ++i_) {                               \
                const int row_ = wm + i_ * 16 + l15;                       \
                const int pc_  = (ksub_ * 4 + quad) ^ (row_ & 7);          \
                af[i_] = *(const bf16x8*)&lA[bu_][row_ * 64 + pc_ * 8];    \
            }                                                              \
            _Pragma("unroll")                                              \
            for (int j_ = 0; j_ < 4; ++j_) {                               \
                const int row_ = wn + j_ * 16 + l15;                       \
                const int pc_  = (ksub_ * 4 + quad) ^ (row_ & 7);          \
                bfr[j_] = *(const bf16x8*)&lB[bu_][row_ * 64 + pc_ * 8];   \
            }                                                              \
            _Pragma("unroll")                                              \
            for (int i_ = 0; i_ < 4; ++i_)                                 \
                _Pragma("unroll")                                          \
                for (int j_ = 0; j_ < 4; ++j_)                             \
                    acc[i_][j_] = __builtin_amdgcn_mfma_f32_16x16x32_bf16( \
                        af[i_], bfr[j_], acc[i_][j_], 0, 0, 0);            \
        }                                                                  \
    }

    // prologue: chunk 0 into buf 0; barrier drains it.
    STAGE(0, 0);
    __syncthreads();

    // steady state: compute chunks t (buf0) and t+1 (buf1); prefetch t+1, t+2.
    // Hazards: readers of a buffer drain lgkmcnt before the end-of-iter
    // barrier; the overwrite of that buffer is after the barrier. ds_reads
    // see staged data because the barrier's implicit vmcnt(0) drained it.
#pragma unroll 1
    for (int t = 0; t < 16; t += 2) {
        STAGE(t + 1, 1);
        COMPUTE(0);
        __syncthreads();
        STAGE(t + 2, 0);
        COMPUTE(1);
        __syncthreads();
    }
    // tail: buf0 holds chunk 16
    STAGE(17, 1);
    COMPUTE(0);
    __syncthreads();
    COMPUTE(1);

#undef STAGE
#undef COMPUTE

    // epilogue: D row = quad*4+reg, col = lane&15 (verified round 1)
#pragma unroll
    for (int i = 0; i < 4; ++i) {
#pragma unroll
        for (int rr = 0; rr < 4; ++rr) {
            const int mrow = mtile * 128 + wm + i * 16 + quad * 4 + rr;
            if (mrow < MTOT) {
                const int oh2 = mrow / OWD;
                const int ow2 = mrow - oh2 * OWD;
                float* op = Out + (((size_t)b * OWD + oh2) * OWD + ow2) * 128 + wn + l15;
#pragma unroll
                for (int j = 0; j < 4; ++j)
                    op[j * 16] = acc[i][j][rr];
            }
        }
    }
}

// ---------------------------------------------------------------------------
// Fallback (ws too small): round-1 kernel, fp32 X with in-kernel cvt.
// ---------------------------------------------------------------------------
__global__ __launch_bounds__(256) void conv_mfma(const float* __restrict__ X,
                                                 const uint16_t* __restrict__ Bt,
                                                 float* __restrict__ Out) {
    __shared__ __align__(16) uint16_t lA[128 * 64];
    __shared__ __align__(16) uint16_t lB[128 * 64];

    const int mtile = blockIdx.x;
    const int b     = blockIdx.y;
    const int tid   = threadIdx.x;
    const int lane  = tid & 63;
    const int wave  = tid >> 6;
    const int wm    = (wave & 1) << 6;
    const int wn    = (wave >> 1) << 6;
    const int l15   = lane & 15;
    const int quad  = lane >> 4;

    const int srow  = tid >> 1;
    const int shalf = tid & 1;

    int m = mtile * 128 + srow;
    if (m >= MTOT) m = MTOT - 1;
    const int oh = m / OWD;
    const int ow = m - oh * OWD;
    const float*    Xb = X + (((size_t)b * 128 + oh) * 128 + ow) * 128;
    const uint16_t* Bb = Bt + ((size_t)b * 128 + srow) * 1152 + shalf * 32;

    f32x4 acc[4][4];
#pragma unroll
    for (int i = 0; i < 4; ++i)
#pragma unroll
        for (int j = 0; j < 4; ++j)
            acc[i][j] = (f32x4){0.f, 0.f, 0.f, 0.f};

    for (int chunk = 0; chunk < 18; ++chunk) {
        const int rs = chunk >> 1;
        const int c0 = (chunk & 1) << 6;
        const int r  = rs / 3;
        const int s  = rs - r * 3;

        __syncthreads();
        {
            const float4* src = (const float4*)(Xb + (r * 128 + s) * 128 + c0 + shalf * 32);
            float4 v[8];
#pragma unroll
            for (int i = 0; i < 8; ++i) v[i] = src[i];
#pragma unroll
            for (int i = 0; i < 4; ++i) {
                uint4 p;
                p.x = pk2(v[2 * i].x, v[2 * i].y);
                p.y = pk2(v[2 * i].z, v[2 * i].w);
                p.z = pk2(v[2 * i + 1].x, v[2 * i + 1].y);
                p.w = pk2(v[2 * i + 1].z, v[2 * i + 1].w);
                const int ci = (shalf * 4 + i) ^ (srow & 7);
                *(uint4*)&lA[srow * 64 + ci * 8] = p;
            }
        }
        {
            const uint4* bsrc = (const uint4*)(Bb + rs * 128 + c0);
#pragma unroll
            for (int i = 0; i < 4; ++i) {
                const uint4 p = bsrc[i];
                const int ci = (shalf * 4 + i) ^ (srow & 7);
                *(uint4*)&lB[srow * 64 + ci * 8] = p;
            }
        }
        __syncthreads();

#pragma unroll
        for (int ksub = 0; ksub < 2; ++ksub) {
            bf16x8 af[4], bfr[4];
#pragma unroll
            for (int i = 0; i < 4; ++i) {
                const int row = wm + i * 16 + l15;
                const int ci  = (ksub * 4 + quad) ^ (row & 7);
                af[i] = *(const bf16x8*)&lA[row * 64 + ci * 8];
            }
#pragma unroll
            for (int j = 0; j < 4; ++j) {
                const int row = wn + j * 16 + l15;
                const int ci  = (ksub * 4 + quad) ^ (row & 7);
                bfr[j] = *(const bf16x8*)&lB[row * 64 + ci * 8];
            }
#pragma unroll
            for (int i = 0; i < 4; ++i)
#pragma unroll
                for (int j = 0; j < 4; ++j)
                    acc[i][j] = __builtin_amdgcn_mfma_f32_16x16x32_bf16(
                        af[i], bfr[j], acc[i][j], 0, 0, 0);
        }
    }

#pragma unroll
    for (int i = 0; i < 4; ++i) {
#pragma unroll
        for (int rr = 0; rr < 4; ++rr) {
            const int mrow = mtile * 128 + wm + i * 16 + quad * 4 + rr;
            if (mrow < MTOT) {
                const int oh2 = mrow / OWD;
                const int ow2 = mrow - oh2 * OWD;
                float* op = Out + (((size_t)b * OWD + oh2) * OWD + ow2) * 128 + wn + l15;
#pragma unroll
                for (int j = 0; j < 4; ++j)
                    op[j * 16] = acc[i][j][rr];
            }
        }
    }
}

extern "C" void kernel_launch(void* const* d_in, const int* in_sizes, int n_in,
                              void* d_out, int out_size, void* d_ws, size_t ws_size,
                              hipStream_t stream) {
    const float* X   = (const float*)d_in[0];   // [16,128,128,128]
    const float* Kin = (const float*)d_in[1];   // [16,3,3,128,128]
    float*       Out = (float*)d_out;           // [16,126,126,128]
    uint16_t*    Bt  = (uint16_t*)d_ws;         // bf16 [16][128][1152]
    uint16_t*    Xbf = Bt + BT_ELEMS;           // bf16 [16][128][128][128]

    kprep<<<dim3(9, 16), 256, 0, stream>>>(Kin, Bt);
    if (ws_size >= WS_NEEDED) {
        xprep<<<XBF_ELEMS / (256 * 8), 256, 0, stream>>>(X, Xbf);
        conv_mfma_a<<<dim3(125, 16), 256, 0, stream>>>(Xbf, Bt, Out);
    } else {
        conv_mfma<<<dim3(125, 16), 256, 0, stream>>>(X, Bt, Out);
    }
}